// Round 2
// baseline (7771.120 us; speedup 1.0000x reference)
//
#include <hip/hip_runtime.h>
#include <math.h>

#define DHID 1024

__device__ __forceinline__ float wred(float v) {
  #pragma unroll
  for (int m = 32; m > 0; m >>= 1) v += __shfl_xor(v, m, 64);
  return v;
}
__device__ __forceinline__ float atanhc(float x) {
  x = fminf(fmaxf(x, -1.0f + 1e-5f), 1.0f - 1e-5f);
  return atanhf(x);
}

// ---------- row norms ----------
__global__ __launch_bounds__(256) void prep(const float* __restrict__ x, const float* __restrict__ h,
    float* __restrict__ nx, float* __restrict__ nh, int B) {
  int row = blockIdx.x * 4 + (threadIdx.x >> 6);
  if (row >= B) return;
  int lane = threadIdx.x & 63;
  size_t base = (size_t)row * DHID;
  const float4* xr = (const float4*)(x + base);
  const float4* hr = (const float4*)(h + base);
  float sx = 0.f, sh = 0.f;
  #pragma unroll
  for (int j = 0; j < 4; ++j) {
    int idx = j * 64 + lane;
    float4 a = xr[idx], b = hr[idx];
    sx += a.x*a.x + a.y*a.y + a.z*a.z + a.w*a.w;
    sh += b.x*b.x + b.y*b.y + b.z*b.z + b.w*b.w;
  }
  sx = wred(sx); sh = wred(sh);
  if (lane == 0) { nx[row] = sqrtf(sx); nh[row] = sqrtf(sh); }
}

// ---------- textbook f32 GEMM: C[M][N] = A[M][K] @ W[K][N] ----------
__global__ __launch_bounds__(256) void gemm_f32(const float* __restrict__ A,
    const float* __restrict__ W, float* __restrict__ C, int M, int N, int K) {
  __shared__ float As[32][33];
  __shared__ float Ws[32][33];
  const int t = threadIdx.x;
  const int tx = t & 31;     // tile col
  const int tg = t >> 5;     // 0..7 row group
  const int row0 = blockIdx.x * 32;
  const int col0 = blockIdx.y * 32;
  float acc[4] = {0.f, 0.f, 0.f, 0.f};
  for (int k0 = 0; k0 < K; k0 += 32) {
    __syncthreads();
    #pragma unroll
    for (int i = 0; i < 4; ++i) {
      As[tg + i*8][tx] = A[(size_t)(row0 + tg + i*8) * K + k0 + tx];
      Ws[tg + i*8][tx] = W[(size_t)(k0 + tg + i*8) * N + col0 + tx];
    }
    __syncthreads();
    #pragma unroll
    for (int kk = 0; kk < 32; ++kk) {
      float w = Ws[kk][tx];
      #pragma unroll
      for (int i = 0; i < 4; ++i) acc[i] += As[tg + i*8][kk] * w;
    }
  }
  #pragma unroll
  for (int i = 0; i < 4; ++i)
    C[(size_t)(row0 + tg + i*8) * N + col0 + tx] = acc[i];
}

// ---------- row helper ----------
__device__ __forceinline__ void load_f32_row(const float* p, int lane, float v[16]) {
  #pragma unroll
  for (int j = 0; j < 4; ++j) {
    int idx = j * 64 + lane;
    float4 a = ((const float4*)p)[idx];
    v[4*j+0] = a.x; v[4*j+1] = a.y; v[4*j+2] = a.z; v[4*j+3] = a.w;
  }
}

struct RowCtx {
  float scale_h, hnc, ath, scale_x, xn, atx;
};

__device__ __forceinline__ RowCtx make_ctx(float n_h, float n_x) {
  RowCtx c;
  c.scale_h = (n_h > 0.9999f) ? 0.9999f / (n_h + 1e-10f) : 1.0f;
  float hn = n_h * c.scale_h;
  c.hnc = fmaxf(hn, 1e-10f);
  c.ath = atanhc(hn);
  float nxc = fmaxf(n_x, 1e-10f);
  c.scale_x = tanhf(nxc) / nxc;
  c.xn = fmaxf(n_x * c.scale_x, 1e-10f);
  c.atx = atanhc(c.xn);
  return c;
}

// one_transform + log0 + sigmoid for one gate (gh = state_raw@W, gx = inputs_raw@U)
__device__ __forceinline__ void gate_sig(const float gh[16], const float gx[16], const float bb[16],
                                         const RowCtx& c, float out[16], float sv[16]) {
  float sh = 0.f, sx = 0.f, dxy = 0.f;
  #pragma unroll
  for (int j = 0; j < 16; ++j) { sh += gh[j]*gh[j]; sx += gx[j]*gx[j]; dxy += gh[j]*gx[j]; }
  sh = wred(sh); sx = wred(sx); dxy = wred(dxy);
  float mhn = fmaxf(c.scale_h * sqrtf(sh), 1e-10f);
  float th  = tanhf(mhn / c.hnc * c.ath);
  float ca  = th * c.scale_h / mhn;           // u[j] = ca*gh[j]
  float mxn = fmaxf(c.scale_x * sqrtf(sx), 1e-10f);
  float tx  = tanhf(mxn / c.xn * c.atx);
  float cb  = tx * c.scale_x / mxn;           // v[j] = cb*gx[j]
  float uv = ca * cb * dxy;
  float u2 = th * th, v2 = tx * tx;
  float den = 1.f + 2.f*uv + u2*v2 + 1e-10f;
  float c1 = (1.f + 2.f*uv + v2) / den * ca;
  float c2 = (1.f - u2) / den * cb;
  float uvb = 0.f, u2s = 0.f, v2b = 0.f;
  #pragma unroll
  for (int j = 0; j < 16; ++j) {
    sv[j] = c1 * gh[j] + c2 * gx[j];
    uvb += sv[j] * bb[j]; u2s += sv[j] * sv[j]; v2b += bb[j] * bb[j];
  }
  uvb = wred(uvb); u2s = wred(u2s); v2b = wred(v2b);
  float den2 = 1.f + 2.f*uvb + u2s*v2b + 1e-10f;
  float d1 = (1.f + 2.f*uvb + v2b) / den2, d2 = (1.f - u2s) / den2;
  float s3 = 0.f;
  #pragma unroll
  for (int j = 0; j < 16; ++j) { sv[j] = d1 * sv[j] + d2 * bb[j]; s3 += sv[j]*sv[j]; }
  s3 = wred(s3);
  float ns = sqrtf(s3);
  float ps = (ns > 0.99999f) ? 0.99999f / (ns + 1e-10f) : 1.0f;
  float nres = fmaxf(ns * ps, 1e-10f);
  float g = atanhc(nres) / nres * ps;
  #pragma unroll
  for (int j = 0; j < 16; ++j) out[j] = 1.0f / (1.0f + expf(-g * sv[j]));
}

// ---------- z gate ----------
__global__ __launch_bounds__(256) void gate_z_k(
    const float* __restrict__ Gh, const float* __restrict__ Gx, const float* __restrict__ bz,
    const float* __restrict__ nxA, const float* __restrict__ nhA,
    float* __restrict__ zout, int B) {
  int row = blockIdx.x * 4 + (threadIdx.x >> 6);
  if (row >= B) return;
  int lane = threadIdx.x & 63;
  size_t base = (size_t)row * DHID;
  RowCtx c = make_ctx(nhA[row], nxA[row]);
  float gh[16], gx[16], bb[16], out[16], sv[16];
  load_f32_row(Gh + base, lane, gh);
  load_f32_row(Gx + base, lane, gx);
  load_f32_row(bz, lane, bb);
  gate_sig(gh, gx, bb, c, out, sv);
  #pragma unroll
  for (int j = 0; j < 4; ++j) {
    int idx = j * 64 + lane;
    ((float4*)(zout + base))[idx] = make_float4(out[4*j], out[4*j+1], out[4*j+2], out[4*j+3]);
  }
}

// ---------- r gate -> r_point_h ----------
__global__ __launch_bounds__(256) void gate_r_k(
    const float* __restrict__ Gh, const float* __restrict__ Gx, const float* __restrict__ br,
    const float* __restrict__ state,
    const float* __restrict__ nxA, const float* __restrict__ nhA,
    float* __restrict__ rph, float* __restrict__ rnA, int B) {
  int row = blockIdx.x * 4 + (threadIdx.x >> 6);
  if (row >= B) return;
  int lane = threadIdx.x & 63;
  size_t base = (size_t)row * DHID;
  RowCtx c = make_ctx(nhA[row], nxA[row]);
  float gh[16], gx[16], bb[16], st[16], out[16], sv[16];
  load_f32_row(Gh + base, lane, gh);
  load_f32_row(Gx + base, lane, gx);
  load_f32_row(br, lane, bb);
  load_f32_row(state + base, lane, st);
  gate_sig(gh, gx, bb, c, out, sv);
  // r_point_h = project(mob_pw(state_proj, r), 1e-4)
  float mxv[16]; float s = 0.f;
  #pragma unroll
  for (int j = 0; j < 16; ++j) { mxv[j] = st[j] * c.scale_h * out[j]; s += mxv[j]*mxv[j]; }
  s = wred(s);
  float mxn = fmaxf(sqrtf(s), 1e-10f);
  float t = tanhf(mxn / c.hnc * c.ath);
  float cc = t / mxn;
  float nrp = t;
  float psc = (nrp > 0.9999f) ? 0.9999f / (nrp + 1e-10f) : 1.0f;
  cc *= psc; nrp *= psc;
  #pragma unroll
  for (int j = 0; j < 4; ++j) {
    int idx = j * 64 + lane;
    ((float4*)(rph + base))[idx] = make_float4(cc*mxv[4*j], cc*mxv[4*j+1], cc*mxv[4*j+2], cc*mxv[4*j+3]);
  }
  if (lane == 0) rnA[row] = nrp;
}

// ---------- final: h_tilde, update, new_h ----------
__global__ __launch_bounds__(256) void final_k(
    const float* __restrict__ Ghh, const float* __restrict__ Ghx,
    const float* __restrict__ state, const float* __restrict__ bh,
    const float* __restrict__ nxA, const float* __restrict__ nhA, const float* __restrict__ rnA,
    float* __restrict__ io, int B) {
  int row = blockIdx.x * 4 + (threadIdx.x >> 6);
  if (row >= B) return;
  int lane = threadIdx.x & 63;
  size_t base = (size_t)row * DHID;
  float n_h = nhA[row], n_x = nxA[row], rn = rnA[row];
  float scale_h = (n_h > 0.9999f) ? 0.9999f / (n_h + 1e-10f) : 1.0f;
  float hn = n_h * scale_h;
  float nxc = fmaxf(n_x, 1e-10f);
  float scale_x = tanhf(nxc) / nxc;
  float xn = fmaxf(n_x * scale_x, 1e-10f);
  float atx = atanhc(xn);
  float hna = fmaxf(rn, 1e-10f);
  float atr = atanhc(rn);

  float gh[16], gx[16], bb[16], st[16], zz[16], sv[16];
  load_f32_row(state + base, lane, st);
  load_f32_row(io + base, lane, zz);   // z from gate_z_k
  load_f32_row(Ghh + base, lane, gh);
  load_f32_row(Ghx + base, lane, gx);
  load_f32_row(bh, lane, bb);

  // a = mob_matmul(r_point_h, Wh); b = mob_matmul(hyp_x, Uh)
  float sh = 0.f, sx = 0.f, dxy = 0.f;
  #pragma unroll
  for (int j = 0; j < 16; ++j) { sh += gh[j]*gh[j]; sx += gx[j]*gx[j]; dxy += gh[j]*gx[j]; }
  sh = wred(sh); sx = wred(sx); dxy = wred(dxy);
  float mhn = fmaxf(sqrtf(sh), 1e-10f);
  float ta = tanhf(mhn / hna * atr);
  float ca = ta / mhn;
  float mxn = fmaxf(scale_x * sqrtf(sx), 1e-10f);
  float tb = tanhf(mxn / xn * atx);
  float cb = tb * scale_x / mxn;
  float uv = ca * cb * dxy;
  float u2 = ta * ta, v2 = tb * tb;
  float den = 1.f + 2.f*uv + u2*v2 + 1e-10f;
  float c1 = (1.f + 2.f*uv + v2) / den * ca;
  float c2 = (1.f - u2) / den * cb;
  float uvb = 0.f, u2s = 0.f, v2b = 0.f;
  #pragma unroll
  for (int j = 0; j < 16; ++j) {
    sv[j] = c1 * gh[j] + c2 * gx[j];
    uvb += sv[j]*bb[j]; u2s += sv[j]*sv[j]; v2b += bb[j]*bb[j];
  }
  uvb = wred(uvb); u2s = wred(u2s); v2b = wred(v2b);
  float den2 = 1.f + 2.f*uvb + u2s*v2b + 1e-10f;
  float d1 = (1.f + 2.f*uvb + v2b) / den2, d2 = (1.f - u2s) / den2;
  float s3 = 0.f;
  #pragma unroll
  for (int j = 0; j < 16; ++j) { sv[j] = d1 * sv[j] + d2 * bb[j]; s3 += sv[j]*sv[j]; }
  s3 = wred(s3);
  float ns = sqrtf(s3);
  float p1 = (ns > 0.99999f) ? 0.99999f / (ns + 1e-10f) : 1.0f;
  float n1 = ns * p1;
  float p2 = (n1 > 0.9999f) ? 0.9999f / (n1 + 1e-10f) : 1.0f;
  float pc = p1 * p2;
  float nht = n1 * p2;
  #pragma unroll
  for (int j = 0; j < 16; ++j) sv[j] *= pc;   // sv = h_tilde

  // m = mob_add(-state_proj, h_tilde)
  float dv = 0.f;
  #pragma unroll
  for (int j = 0; j < 16; ++j) dv += st[j] * sv[j];
  dv = wred(dv);
  float uv2 = -scale_h * dv;
  float u2m = hn * hn, v2m = nht * nht;
  float den3 = 1.f + 2.f*uv2 + u2m*v2m + 1e-10f;
  float e1 = -(1.f + 2.f*uv2 + v2m) / den3 * scale_h;  // * st
  float e2 = (1.f - u2m) / den3;                       // * sv
  float mv[16]; float sm = 0.f;
  #pragma unroll
  for (int j = 0; j < 16; ++j) { mv[j] = e1*st[j] + e2*sv[j]; sm += mv[j]*mv[j]; }
  sm = wred(sm);
  float vn = fmaxf(sqrtf(sm), 1e-10f);
  float atv = atanhc(vn);
  // update = mob_pw(m, z)
  float mx2[16]; float s4 = 0.f;
  #pragma unroll
  for (int j = 0; j < 16; ++j) { mx2[j] = mv[j]*zz[j]; s4 += mx2[j]*mx2[j]; }
  s4 = wred(s4);
  float mxn2 = fmaxf(sqrtf(s4), 1e-10f);
  float tu = tanhf(mxn2 / vn * atv);
  float cu2 = tu / mxn2;                               // upd = cu2*mx2
  // new_h = project(mob_add(state_proj, upd), 1e-5)
  float d5 = 0.f;
  #pragma unroll
  for (int j = 0; j < 16; ++j) d5 += st[j]*mx2[j];
  d5 = wred(d5);
  float uv3 = scale_h * cu2 * d5;
  float u2f = hn * hn, v2f = tu * tu;
  float den4 = 1.f + 2.f*uv3 + u2f*v2f + 1e-10f;
  float f1 = (1.f + 2.f*uv3 + v2f) / den4 * scale_h;   // * st
  float f2 = (1.f - u2f) / den4 * cu2;                 // * mx2
  float nh4[16]; float s5 = 0.f;
  #pragma unroll
  for (int j = 0; j < 16; ++j) { nh4[j] = f1*st[j] + f2*mx2[j]; s5 += nh4[j]*nh4[j]; }
  s5 = wred(s5);
  float nf = sqrtf(s5);
  float pf = (nf > 0.99999f) ? 0.99999f / (nf + 1e-10f) : 1.0f;
  #pragma unroll
  for (int j = 0; j < 4; ++j) {
    int idx = j * 64 + lane;
    ((float4*)(io + base))[idx] = make_float4(pf*nh4[4*j], pf*nh4[4*j+1], pf*nh4[4*j+2], pf*nh4[4*j+3]);
  }
}

extern "C" void kernel_launch(void* const* d_in, const int* in_sizes, int n_in,
                              void* d_out, int out_size, void* d_ws, size_t ws_size,
                              hipStream_t stream) {
  const float* inputs = (const float*)d_in[0];
  const float* state  = (const float*)d_in[1];
  const float* Wz = (const float*)d_in[2];
  const float* Uz = (const float*)d_in[3];
  const float* bz = (const float*)d_in[4];
  const float* Wr = (const float*)d_in[5];
  const float* Ur = (const float*)d_in[6];
  const float* br = (const float*)d_in[7];
  const float* Wh = (const float*)d_in[8];
  const float* Uh = (const float*)d_in[9];
  const float* bh = (const float*)d_in[10];
  const int B = in_sizes[0] / DHID;
  const size_t MD = (size_t)B * DHID;

  char* p = (char*)d_ws;
  float* G0   = (float*)p; p += MD * 4;
  float* G2   = (float*)p; p += MD * 4;
  float* rphf = (float*)p; p += MD * 4;
  float* nx   = (float*)p; p += (size_t)B * 4;
  float* nh   = (float*)p; p += (size_t)B * 4;
  float* rn   = (float*)p; p += (size_t)B * 4;
  if ((size_t)(p - (char*)d_ws) > ws_size) return;

  float* zbuf = (float*)d_out;
  dim3 gg(B / 32, DHID / 32);

  prep<<<B/4, 256, 0, stream>>>(inputs, state, nx, nh, B);

  gemm_f32<<<gg, 256, 0, stream>>>(state,  Wz, G0, B, DHID, DHID);
  gemm_f32<<<gg, 256, 0, stream>>>(inputs, Uz, G2, B, DHID, DHID);
  gate_z_k<<<B/4, 256, 0, stream>>>(G0, G2, bz, nx, nh, zbuf, B);

  gemm_f32<<<gg, 256, 0, stream>>>(state,  Wr, G0, B, DHID, DHID);
  gemm_f32<<<gg, 256, 0, stream>>>(inputs, Ur, G2, B, DHID, DHID);
  gate_r_k<<<B/4, 256, 0, stream>>>(G0, G2, br, state, nx, nh, rphf, rn, B);

  gemm_f32<<<gg, 256, 0, stream>>>(rphf,   Wh, G0, B, DHID, DHID);
  gemm_f32<<<gg, 256, 0, stream>>>(inputs, Uh, G2, B, DHID, DHID);
  final_k<<<B/4, 256, 0, stream>>>(G0, G2, state, bh, nx, nh, rn, zbuf, B);
}

// Round 3
// 474.315 us; speedup vs baseline: 16.3839x; 16.3839x over previous
//
#include <hip/hip_runtime.h>
#include <math.h>

typedef unsigned short u16;
typedef __attribute__((ext_vector_type(8))) short bf16x8;
typedef __attribute__((ext_vector_type(4))) float f32x4;

#define DHID 1024

__device__ __forceinline__ u16 f2bf(float f) {
  union { float f; unsigned u; } v; v.f = f;
  unsigned u = v.u;
  u = (u + 0x7fffu + ((u >> 16) & 1u)) >> 16;
  return (u16)u;
}
__device__ __forceinline__ float bf2f(u16 h) {
  union { unsigned u; float f; } v; v.u = ((unsigned)h) << 16;
  return v.f;
}
__device__ __forceinline__ float wred(float v) {
  #pragma unroll
  for (int m = 32; m > 0; m >>= 1) v += __shfl_xor(v, m, 64);
  return v;
}
__device__ __forceinline__ float atanhc(float x) {
  x = fminf(fmaxf(x, -1.0f + 1e-5f), 1.0f - 1e-5f);
  return atanhf(x);
}

// ---------- weight convert + transpose: dst[n][k] = bf16(src[k][n]) ----------
__global__ __launch_bounds__(256) void wconv(const float* __restrict__ src, u16* __restrict__ dst) {
  __shared__ float t[32][33];
  int bx = blockIdx.x * 32, by = blockIdx.y * 32;
  int tx = threadIdx.x, ty = threadIdx.y;
  #pragma unroll
  for (int r = 0; r < 32; r += 8)
    t[ty + r][tx] = src[(size_t)(by + ty + r) * DHID + bx + tx];
  __syncthreads();
  #pragma unroll
  for (int r = 0; r < 32; r += 8)
    dst[(size_t)(bx + ty + r) * DHID + by + tx] = f2bf(t[tx][ty + r]);
}

// ---------- prep: row norms + bf16 casts ----------
__global__ __launch_bounds__(256) void prep(const float* __restrict__ x, const float* __restrict__ h,
    u16* __restrict__ xb, u16* __restrict__ hb, float* __restrict__ nx, float* __restrict__ nh, int B) {
  int row = blockIdx.x * 4 + (threadIdx.x >> 6);
  if (row >= B) return;
  int lane = threadIdx.x & 63;
  size_t base = (size_t)row * DHID;
  const float4* xr = (const float4*)(x + base);
  const float4* hr = (const float4*)(h + base);
  ushort4* xo = (ushort4*)(xb + base);
  ushort4* ho = (ushort4*)(hb + base);
  float sx = 0.f, sh = 0.f;
  #pragma unroll
  for (int j = 0; j < 4; ++j) {
    int idx = j * 64 + lane;
    float4 a = xr[idx], b = hr[idx];
    sx += a.x*a.x + a.y*a.y + a.z*a.z + a.w*a.w;
    sh += b.x*b.x + b.y*b.y + b.z*b.z + b.w*b.w;
    xo[idx] = make_ushort4(f2bf(a.x), f2bf(a.y), f2bf(a.z), f2bf(a.w));
    ho[idx] = make_ushort4(f2bf(b.x), f2bf(b.y), f2bf(b.z), f2bf(b.w));
  }
  sx = wred(sx); sh = wred(sh);
  if (lane == 0) { nx[row] = sqrtf(sx); nh[row] = sqrtf(sh); }
}

// ---------- bf16 MFMA GEMM: C[M][N] = A[M][K] @ Bt[N][K]^T, bf16 out ----------
__global__ __launch_bounds__(256) void gemm_bf16(const u16* __restrict__ A,
    const u16* __restrict__ Bt, u16* __restrict__ C, int M, int N, int K) {
  __shared__ __align__(16) u16 As[128][72];
  __shared__ __align__(16) u16 Bs[128][72];
  const int tid = threadIdx.x;
  const int lane = tid & 63;
  const int wid = tid >> 6;
  const int wr = (wid >> 1) * 64;
  const int wc = (wid & 1) * 64;
  const int l15 = lane & 15;
  const int koff = (lane >> 4) * 8;
  const size_t abase = (size_t)(blockIdx.x * 128) * K;
  const size_t bbase = (size_t)(blockIdx.y * 128) * K;
  f32x4 acc[4][4] = {};
  for (int k0 = 0; k0 < K; k0 += 64) {
    __syncthreads();
    #pragma unroll
    for (int i = 0; i < 4; ++i) {
      int idx = tid + i * 256;
      int r = idx >> 3, kc = (idx & 7) * 8;
      *(uint4*)&As[r][kc] = *(const uint4*)(A + abase + (size_t)r * K + k0 + kc);
      *(uint4*)&Bs[r][kc] = *(const uint4*)(Bt + bbase + (size_t)r * K + k0 + kc);
    }
    __syncthreads();
    #pragma unroll
    for (int ks = 0; ks < 64; ks += 32) {
      bf16x8 af[4], bg[4];
      #pragma unroll
      for (int m = 0; m < 4; ++m) af[m] = *(const bf16x8*)&As[wr + m*16 + l15][ks + koff];
      #pragma unroll
      for (int n = 0; n < 4; ++n) bg[n] = *(const bf16x8*)&Bs[wc + n*16 + l15][ks + koff];
      #pragma unroll
      for (int m = 0; m < 4; ++m)
        #pragma unroll
        for (int n = 0; n < 4; ++n)
          acc[m][n] = __builtin_amdgcn_mfma_f32_16x16x32_bf16(af[m], bg[n], acc[m][n], 0, 0, 0);
    }
  }
  const int r4 = (lane >> 4) * 4;
  #pragma unroll
  for (int m = 0; m < 4; ++m)
    #pragma unroll
    for (int n = 0; n < 4; ++n) {
      size_t col = (size_t)blockIdx.y * 128 + wc + n * 16 + l15;
      #pragma unroll
      for (int j = 0; j < 4; ++j) {
        size_t row = (size_t)blockIdx.x * 128 + wr + m * 16 + r4 + j;
        C[row * N + col] = f2bf(acc[m][n][j]);
      }
    }
}

// ---------- row helpers ----------
__device__ __forceinline__ void load_bf16_row(const u16* p, int lane, float v[16]) {
  #pragma unroll
  for (int j = 0; j < 4; ++j) {
    int idx = j * 64 + lane;
    ushort4 a = ((const ushort4*)p)[idx];
    v[4*j+0] = bf2f(a.x); v[4*j+1] = bf2f(a.y); v[4*j+2] = bf2f(a.z); v[4*j+3] = bf2f(a.w);
  }
}
__device__ __forceinline__ void load_f32_row(const float* p, int lane, float v[16]) {
  #pragma unroll
  for (int j = 0; j < 4; ++j) {
    int idx = j * 64 + lane;
    float4 a = ((const float4*)p)[idx];
    v[4*j+0] = a.x; v[4*j+1] = a.y; v[4*j+2] = a.z; v[4*j+3] = a.w;
  }
}

struct RowCtx {
  float scale_h, hnc, ath, scale_x, xn, atx;
};

__device__ __forceinline__ RowCtx make_ctx(float n_h, float n_x) {
  RowCtx c;
  c.scale_h = (n_h > 0.9999f) ? 0.9999f / (n_h + 1e-10f) : 1.0f;
  float hn = n_h * c.scale_h;
  c.hnc = fmaxf(hn, 1e-10f);
  c.ath = atanhc(hn);
  float nxc = fmaxf(n_x, 1e-10f);
  c.scale_x = tanhf(nxc) / nxc;
  c.xn = fmaxf(n_x * c.scale_x, 1e-10f);
  c.atx = atanhc(c.xn);
  return c;
}

// one_transform + log0 + sigmoid for one gate (gh = state_raw@W, gx = inputs_raw@U)
__device__ __forceinline__ void gate_sig(const float gh[16], const float gx[16], const float bb[16],
                                         const RowCtx& c, float out[16], float sv[16]) {
  float sh = 0.f, sx = 0.f, dxy = 0.f;
  #pragma unroll
  for (int j = 0; j < 16; ++j) { sh += gh[j]*gh[j]; sx += gx[j]*gx[j]; dxy += gh[j]*gx[j]; }
  sh = wred(sh); sx = wred(sx); dxy = wred(dxy);
  float mhn = fmaxf(c.scale_h * sqrtf(sh), 1e-10f);
  float th  = tanhf(mhn / c.hnc * c.ath);
  float ca  = th * c.scale_h / mhn;           // u[j] = ca*gh[j]
  float mxn = fmaxf(c.scale_x * sqrtf(sx), 1e-10f);
  float tx  = tanhf(mxn / c.xn * c.atx);
  float cb  = tx * c.scale_x / mxn;           // v[j] = cb*gx[j]
  float uv = ca * cb * dxy;
  float u2 = th * th, v2 = tx * tx;
  float den = 1.f + 2.f*uv + u2*v2 + 1e-10f;
  float c1 = (1.f + 2.f*uv + v2) / den * ca;
  float c2 = (1.f - u2) / den * cb;
  float uvb = 0.f, u2s = 0.f, v2b = 0.f;
  #pragma unroll
  for (int j = 0; j < 16; ++j) {
    sv[j] = c1 * gh[j] + c2 * gx[j];
    uvb += sv[j] * bb[j]; u2s += sv[j] * sv[j]; v2b += bb[j] * bb[j];
  }
  uvb = wred(uvb); u2s = wred(u2s); v2b = wred(v2b);
  float den2 = 1.f + 2.f*uvb + u2s*v2b + 1e-10f;
  float d1 = (1.f + 2.f*uvb + v2b) / den2, d2 = (1.f - u2s) / den2;
  float s3 = 0.f;
  #pragma unroll
  for (int j = 0; j < 16; ++j) { sv[j] = d1 * sv[j] + d2 * bb[j]; s3 += sv[j]*sv[j]; }
  s3 = wred(s3);
  float ns = sqrtf(s3);
  float ps = (ns > 0.99999f) ? 0.99999f / (ns + 1e-10f) : 1.0f;
  float nres = fmaxf(ns * ps, 1e-10f);
  float g = atanhc(nres) / nres * ps;
  #pragma unroll
  for (int j = 0; j < 16; ++j) out[j] = 1.0f / (1.0f + expf(-g * sv[j]));
}

// ---------- gates: z (-> d_out), r, r_point_h (-> bf16), rn ----------
__global__ __launch_bounds__(256) void gates_k(
    const u16* __restrict__ Gzh, const u16* __restrict__ Gzx,
    const u16* __restrict__ Grh, const u16* __restrict__ Grx,
    const float* __restrict__ state, const float* __restrict__ bz, const float* __restrict__ br,
    const float* __restrict__ nxA, const float* __restrict__ nhA,
    float* __restrict__ zout, u16* __restrict__ rphb, float* __restrict__ rnA, int B) {
  int row = blockIdx.x * 4 + (threadIdx.x >> 6);
  if (row >= B) return;
  int lane = threadIdx.x & 63;
  size_t base = (size_t)row * DHID;
  RowCtx c = make_ctx(nhA[row], nxA[row]);

  float gh[16], gx[16], bb[16], st[16], out[16], sv[16];
  load_f32_row(state + base, lane, st);

  // z gate
  load_bf16_row(Gzh + base, lane, gh);
  load_bf16_row(Gzx + base, lane, gx);
  load_f32_row(bz, lane, bb);   // bias [1,DHID]: broadcast across rows
  gate_sig(gh, gx, bb, c, out, sv);
  #pragma unroll
  for (int j = 0; j < 4; ++j) {
    int idx = j * 64 + lane;
    ((float4*)(zout + base))[idx] = make_float4(out[4*j], out[4*j+1], out[4*j+2], out[4*j+3]);
  }

  // r gate
  load_bf16_row(Grh + base, lane, gh);
  load_bf16_row(Grx + base, lane, gx);
  load_f32_row(br, lane, bb);
  gate_sig(gh, gx, bb, c, out, sv);

  // r_point_h = project(mob_pw(state_proj, r), 1e-4)
  float mxv[16]; float s = 0.f;
  #pragma unroll
  for (int j = 0; j < 16; ++j) { mxv[j] = st[j] * c.scale_h * out[j]; s += mxv[j]*mxv[j]; }
  s = wred(s);
  float mxn = fmaxf(sqrtf(s), 1e-10f);
  float t = tanhf(mxn / c.hnc * c.ath);
  float cc = t / mxn;
  float nrp = t;
  float psc = (nrp > 0.9999f) ? 0.9999f / (nrp + 1e-10f) : 1.0f;
  cc *= psc; nrp *= psc;
  #pragma unroll
  for (int j = 0; j < 4; ++j) {
    int idx = j * 64 + lane;
    ((ushort4*)(rphb + base))[idx] = make_ushort4(
        f2bf(cc*mxv[4*j+0]), f2bf(cc*mxv[4*j+1]), f2bf(cc*mxv[4*j+2]), f2bf(cc*mxv[4*j+3]));
  }
  if (lane == 0) rnA[row] = nrp;
}

// ---------- final: h_tilde, update, new_h ----------
__global__ __launch_bounds__(256) void final_k(
    const u16* __restrict__ Ghh, const u16* __restrict__ Ghx,
    const float* __restrict__ state, const float* __restrict__ bh,
    const float* __restrict__ nxA, const float* __restrict__ nhA, const float* __restrict__ rnA,
    float* __restrict__ io, int B) {
  int row = blockIdx.x * 4 + (threadIdx.x >> 6);
  if (row >= B) return;
  int lane = threadIdx.x & 63;
  size_t base = (size_t)row * DHID;
  float n_h = nhA[row], n_x = nxA[row], rn = rnA[row];
  float scale_h = (n_h > 0.9999f) ? 0.9999f / (n_h + 1e-10f) : 1.0f;
  float hn = n_h * scale_h;
  float nxc = fmaxf(n_x, 1e-10f);
  float scale_x = tanhf(nxc) / nxc;
  float xn = fmaxf(n_x * scale_x, 1e-10f);
  float atx = atanhc(xn);
  float hna = fmaxf(rn, 1e-10f);
  float atr = atanhc(rn);

  float gh[16], gx[16], bb[16], st[16], zz[16], sv[16];
  load_f32_row(state + base, lane, st);
  load_f32_row(io + base, lane, zz);   // z from gates_k
  load_bf16_row(Ghh + base, lane, gh);
  load_bf16_row(Ghx + base, lane, gx);
  load_f32_row(bh, lane, bb);

  // a = mob_matmul(r_point_h, Wh); b = mob_matmul(hyp_x, Uh)
  float sh = 0.f, sx = 0.f, dxy = 0.f;
  #pragma unroll
  for (int j = 0; j < 16; ++j) { sh += gh[j]*gh[j]; sx += gx[j]*gx[j]; dxy += gh[j]*gx[j]; }
  sh = wred(sh); sx = wred(sx); dxy = wred(dxy);
  float mhn = fmaxf(sqrtf(sh), 1e-10f);
  float ta = tanhf(mhn / hna * atr);
  float ca = ta / mhn;
  float mxn = fmaxf(scale_x * sqrtf(sx), 1e-10f);
  float tb = tanhf(mxn / xn * atx);
  float cb = tb * scale_x / mxn;
  float uv = ca * cb * dxy;
  float u2 = ta * ta, v2 = tb * tb;
  float den = 1.f + 2.f*uv + u2*v2 + 1e-10f;
  float c1 = (1.f + 2.f*uv + v2) / den * ca;
  float c2 = (1.f - u2) / den * cb;
  float uvb = 0.f, u2s = 0.f, v2b = 0.f;
  #pragma unroll
  for (int j = 0; j < 16; ++j) {
    sv[j] = c1 * gh[j] + c2 * gx[j];
    uvb += sv[j]*bb[j]; u2s += sv[j]*sv[j]; v2b += bb[j]*bb[j];
  }
  uvb = wred(uvb); u2s = wred(u2s); v2b = wred(v2b);
  float den2 = 1.f + 2.f*uvb + u2s*v2b + 1e-10f;
  float d1 = (1.f + 2.f*uvb + v2b) / den2, d2 = (1.f - u2s) / den2;
  float s3 = 0.f;
  #pragma unroll
  for (int j = 0; j < 16; ++j) { sv[j] = d1 * sv[j] + d2 * bb[j]; s3 += sv[j]*sv[j]; }
  s3 = wred(s3);
  float ns = sqrtf(s3);
  float p1 = (ns > 0.99999f) ? 0.99999f / (ns + 1e-10f) : 1.0f;
  float n1 = ns * p1;
  float p2 = (n1 > 0.9999f) ? 0.9999f / (n1 + 1e-10f) : 1.0f;
  float pc = p1 * p2;
  float nht = n1 * p2;
  #pragma unroll
  for (int j = 0; j < 16; ++j) sv[j] *= pc;   // sv = h_tilde

  // m = mob_add(-state_proj, h_tilde)
  float dv = 0.f;
  #pragma unroll
  for (int j = 0; j < 16; ++j) dv += st[j] * sv[j];
  dv = wred(dv);
  float uv2 = -scale_h * dv;
  float u2m = hn * hn, v2m = nht * nht;
  float den3 = 1.f + 2.f*uv2 + u2m*v2m + 1e-10f;
  float e1 = -(1.f + 2.f*uv2 + v2m) / den3 * scale_h;  // * st
  float e2 = (1.f - u2m) / den3;                       // * sv
  float mv[16]; float sm = 0.f;
  #pragma unroll
  for (int j = 0; j < 16; ++j) { mv[j] = e1*st[j] + e2*sv[j]; sm += mv[j]*mv[j]; }
  sm = wred(sm);
  float vn = fmaxf(sqrtf(sm), 1e-10f);
  float atv = atanhc(vn);
  // update = mob_pw(m, z)
  float mx2[16]; float s4 = 0.f;
  #pragma unroll
  for (int j = 0; j < 16; ++j) { mx2[j] = mv[j]*zz[j]; s4 += mx2[j]*mx2[j]; }
  s4 = wred(s4);
  float mxn2 = fmaxf(sqrtf(s4), 1e-10f);
  float tu = tanhf(mxn2 / vn * atv);
  float cu2 = tu / mxn2;                               // upd = cu2*mx2
  // new_h = project(mob_add(state_proj, upd), 1e-5)
  float d5 = 0.f;
  #pragma unroll
  for (int j = 0; j < 16; ++j) d5 += st[j]*mx2[j];
  d5 = wred(d5);
  float uv3 = scale_h * cu2 * d5;
  float u2f = hn * hn, v2f = tu * tu;
  float den4 = 1.f + 2.f*uv3 + u2f*v2f + 1e-10f;
  float f1 = (1.f + 2.f*uv3 + v2f) / den4 * scale_h;   // * st
  float f2 = (1.f - u2f) / den4 * cu2;                 // * mx2
  float nh4[16]; float s5 = 0.f;
  #pragma unroll
  for (int j = 0; j < 16; ++j) { nh4[j] = f1*st[j] + f2*mx2[j]; s5 += nh4[j]*nh4[j]; }
  s5 = wred(s5);
  float nf = sqrtf(s5);
  float pf = (nf > 0.99999f) ? 0.99999f / (nf + 1e-10f) : 1.0f;
  #pragma unroll
  for (int j = 0; j < 4; ++j) {
    int idx = j * 64 + lane;
    ((float4*)(io + base))[idx] = make_float4(pf*nh4[4*j], pf*nh4[4*j+1], pf*nh4[4*j+2], pf*nh4[4*j+3]);
  }
}

extern "C" void kernel_launch(void* const* d_in, const int* in_sizes, int n_in,
                              void* d_out, int out_size, void* d_ws, size_t ws_size,
                              hipStream_t stream) {
  const float* inputs = (const float*)d_in[0];
  const float* state  = (const float*)d_in[1];
  const float* Wz = (const float*)d_in[2];
  const float* Uz = (const float*)d_in[3];
  const float* bz = (const float*)d_in[4];
  const float* Wr = (const float*)d_in[5];
  const float* Ur = (const float*)d_in[6];
  const float* br = (const float*)d_in[7];
  const float* Wh = (const float*)d_in[8];
  const float* Uh = (const float*)d_in[9];
  const float* bh = (const float*)d_in[10];
  const int B = in_sizes[0] / DHID;
  const size_t MD = (size_t)B * DHID;

  char* p = (char*)d_ws;
  u16* xb = (u16*)p;  p += MD * 2;
  u16* hb = (u16*)p;  p += MD * 2;            // state bf16, later r_point_h bf16
  u16* Wt0 = (u16*)p; p += (size_t)DHID*DHID*2;
  u16* Wt1 = (u16*)p; p += (size_t)DHID*DHID*2;
  u16* Wt2 = (u16*)p; p += (size_t)DHID*DHID*2;
  u16* Wt3 = (u16*)p; p += (size_t)DHID*DHID*2;
  u16* Wt4 = (u16*)p; p += (size_t)DHID*DHID*2;
  u16* Wt5 = (u16*)p; p += (size_t)DHID*DHID*2;
  u16* G0 = (u16*)p;  p += MD * 2;
  u16* G1 = (u16*)p;  p += MD * 2;
  u16* G2 = (u16*)p;  p += MD * 2;
  u16* G3 = (u16*)p;  p += MD * 2;
  float* nx = (float*)p; p += (size_t)B * 4;
  float* nh = (float*)p; p += (size_t)B * 4;
  float* rn = (float*)p; p += (size_t)B * 4;
  if ((size_t)(p - (char*)d_ws) > ws_size) return;

  float* zbuf = (float*)d_out;

  prep<<<B/4, 256, 0, stream>>>(inputs, state, xb, hb, nx, nh, B);

  dim3 tb(32, 8), tg(DHID/32, DHID/32);
  wconv<<<tg, tb, 0, stream>>>(Wz, Wt0);
  wconv<<<tg, tb, 0, stream>>>(Wr, Wt1);
  wconv<<<tg, tb, 0, stream>>>(Wh, Wt2);
  wconv<<<tg, tb, 0, stream>>>(Uz, Wt3);
  wconv<<<tg, tb, 0, stream>>>(Ur, Wt4);
  wconv<<<tg, tb, 0, stream>>>(Uh, Wt5);

  dim3 gg(B/128, DHID/128);
  gemm_bf16<<<gg, 256, 0, stream>>>(hb, Wt0, G0, B, DHID, DHID);  // state@Wz
  gemm_bf16<<<gg, 256, 0, stream>>>(hb, Wt1, G1, B, DHID, DHID);  // state@Wr
  gemm_bf16<<<gg, 256, 0, stream>>>(xb, Wt3, G2, B, DHID, DHID);  // inputs@Uz
  gemm_bf16<<<gg, 256, 0, stream>>>(xb, Wt4, G3, B, DHID, DHID);  // inputs@Ur

  gates_k<<<B/4, 256, 0, stream>>>(G0, G2, G1, G3, state, bz, br, nx, nh, zbuf, hb, rn, B);

  gemm_bf16<<<gg, 256, 0, stream>>>(hb, Wt2, G0, B, DHID, DHID);  // r_point_h@Wh
  gemm_bf16<<<gg, 256, 0, stream>>>(xb, Wt5, G1, B, DHID, DHID);  // inputs@Uh

  final_k<<<B/4, 256, 0, stream>>>(G0, G1, state, bh, nx, nh, rn, zbuf, B);
}